// Round 6
// baseline (6295.171 us; speedup 1.0000x reference)
//
#include <hip/hip_runtime.h>
#include <math.h>

#define NSW 12  // convergence-verified budget (R2/R5: absmax at bf16 floor)

__device__ __forceinline__ float bperm_f(int addr4, float v) {
    return __int_as_float(__builtin_amdgcn_ds_bpermute(addr4, __float_as_int(v)));
}

// One-sided (Hestenes) Jacobi, circle-method tournament (R2/R5-verified),
// QUARTER-column layout: 4 waves per matrix, wave w owns rows [16w,16w+16),
// lane l holds 16 floats of column l. Main-loop live set ~50 VGPRs — fits
// under the allocator's observed 64-reg preference, so no rematerialized
// bpermutes (R2/R5: 2x DS traffic) and no scratch spill (R4/R5: +92..117MB).
// Gram gamma combined across 4 waves via double-buffered gbuf (canonical
// (g0+g1)+(g2+g3) -> bit-identical on every copy of the pair).
__global__ __launch_bounds__(256, 4) void logeig_kernel(
    const float* __restrict__ Xg, float* __restrict__ out)
{
    __shared__ __align__(16) float Wc[64 * 20];  // epilogue chunk (16 cols, pad 20)
    __shared__ float gbuf[2][4][64];             // [parity][wave][column] partials
    __shared__ float hlds[64];

    const int tid = threadIdx.x;
    const int w   = tid >> 6;     // wave: rows [16w, 16w+16)
    const int l   = tid & 63;     // owned column
    const int b   = blockIdx.x;

    // ---- load rows [16w,16w+16) of column l (X symmetric -> row l span) ----
    float x[16];
    {
        const float4* __restrict__ Xb4 =
            (const float4*)(Xg + (size_t)b * 4096 + (size_t)l * 64 + 16 * w);
        #pragma unroll
        for (int q = 0; q < 4; ++q) {
            float4 v = Xb4[q];
            x[4 * q + 0] = v.x; x[4 * q + 1] = v.y;
            x[4 * q + 2] = v.z; x[4 * q + 3] = v.w;
        }
    }

    // canonical 16-element self-dot (identical formula in every wave)
    #define SELFDOT16(res)                                            \
        {                                                             \
            float a0 = 0.f, a1 = 0.f, a2 = 0.f, a3 = 0.f;             \
            _Pragma("unroll")                                         \
            for (int k = 0; k < 16; k += 4) {                         \
                a0 = fmaf(x[k + 0], x[k + 0], a0);                    \
                a1 = fmaf(x[k + 1], x[k + 1], a1);                    \
                a2 = fmaf(x[k + 2], x[k + 2], a2);                    \
                a3 = fmaf(x[k + 3], x[k + 3], a3);                    \
            }                                                         \
            res = (a0 + a1) + (a2 + a3);                              \
        }

    // ---- initial squared norm: 4 partials combined canonically ----
    float d;
    {
        float p; SELFDOT16(p);
        gbuf[0][w][l] = p;
        __syncthreads();
        const float g0 = gbuf[0][0][l], g1 = gbuf[0][1][l];
        const float g2 = gbuf[0][2][l], g3 = gbuf[0][3][l];
        d = (g0 + g1) + (g2 + g3);
    }

    // ---- tournament state (identical formulas to R2/R5, per column l) ----
    const int m  = l - 1;                       // label; -1 for fixed player col 0
    int pm = (l == 0) ? 0 : ((63 - m) % 63);    // (r - m) mod 63 at r=0
    int p0 = 0;                                 // 32*r mod 63

    for (int sweep = 0; sweep < NSW; ++sweep) {
        for (int r = 0; r < 63; ++r) {
            const int prt  = (l == 0) ? (p0 + 1)
                                      : ((pm == m) ? 0 : (pm + 1));
            const int prt4 = prt << 2;

            // fetch partner quarter-column + Gram partial (this wave's 16 rows)
            float xp[16];
            float a0 = 0.f, a1 = 0.f, a2 = 0.f, a3 = 0.f;
            #pragma unroll
            for (int k = 0; k < 16; k += 4) {
                xp[k + 0] = bperm_f(prt4, x[k + 0]);
                xp[k + 1] = bperm_f(prt4, x[k + 1]);
                xp[k + 2] = bperm_f(prt4, x[k + 2]);
                xp[k + 3] = bperm_f(prt4, x[k + 3]);
                a0 = fmaf(x[k + 0], xp[k + 0], a0);
                a1 = fmaf(x[k + 1], xp[k + 1], a1);
                a2 = fmaf(x[k + 2], xp[k + 2], a2);
                a3 = fmaf(x[k + 3], xp[k + 3], a3);
            }
            const float gp = (a0 + a1) + (a2 + a3);  // this wave's quarter of gamma
            const float dq = bperm_f(prt4, d);       // partner's full norm (replicated)

            gbuf[r & 1][w][l] = gp;
            __syncthreads();
            const float g0 = gbuf[r & 1][0][l], g1 = gbuf[r & 1][1][l];
            const float g2 = gbuf[r & 1][2][l], g3 = gbuf[r & 1][3][l];
            const float g  = (g0 + g1) + (g2 + g3); // bit-identical on all copies

            const bool lo = l < prt;
            const bool ok = fabsf(g) > 1e-30f;

            // angle from the LO column's perspective (identical on all copies)
            const float num  = lo ? (dq - d) : (d - dq);
            const float zeta = num / (2.f * g);
            const float az   = fabsf(zeta);
            float tl = 1.f / (az + sqrtf(fmaf(az, az, 1.f)));
            tl = (zeta >= 0.f) ? tl : -tl;           // lo-side t
            float tn = lo ? tl : -tl;                // own signed t (hi negates)
            tn = ok ? tn : 0.f;
            const float c = rsqrtf(fmaf(tn, tn, 1.f));
            const float s = c * tn;

            // Rutishauser norm update (identical on every copy)
            d = fmaf(-tn, g, d);

            // quarter-column update
            #pragma unroll
            for (int k = 0; k < 16; ++k)
                x[k] = fmaf(-s, xp[k], c * x[k]);

            // advance tournament state
            pm = (pm + 1 == 63) ? 0 : (pm + 1);
            p0 += 32; if (p0 >= 63) p0 -= 63;
        }

        // sweep boundary: resync squared norm from actual partials.
        // barrier first: rotation r=62 (parity 0) read gbuf[0] after its own
        // barrier; drain those reads before overwriting.
        float p; SELFDOT16(p);
        __syncthreads();
        gbuf[0][w][l] = p;
        __syncthreads();
        const float g0 = gbuf[0][0][l], g1 = gbuf[0][1][l];
        const float g2 = gbuf[0][2][l], g3 = gbuf[0][3][l];
        d = (g0 + g1) + (g2 + g3);
    }
    #undef SELFDOT16

    // ---- epilogue: out = sum_c h_c w_c w_c^T, 16 columns per chunk ----
    const float alpha = fmaxf(d, 1e-12f);
    const float h = 0.5f * logf(alpha) / alpha;
    if (w == 0) hlds[l] = h;   // identical value on all waves

    float acc[16];
    #pragma unroll
    for (int k = 0; k < 16; ++k) acc[k] = 0.f;

    const int cg = l >> 4;   // chunk containing this lane's column
    const int cc = l & 15;   // column index within chunk

    for (int gi = 0; gi < 4; ++gi) {
        __syncthreads();     // hlds visible (gi=0) / Wc WAR (gi>0)
        if (cg == gi) {
            #pragma unroll
            for (int k = 0; k < 16; ++k) Wc[(16 * w + k) * 20 + cc] = x[k];
        }
        __syncthreads();

        // r0[j] = h_{16gi+j} * w_{16gi+j}[l]
        float r0[16];
        #pragma unroll
        for (int j = 0; j < 16; ++j) r0[j] = Wc[l * 20 + j] * hlds[gi * 16 + j];

        // acc[k] += sum_j Wc[16w+k][j] * r0[j]  (uniform b128 broadcast reads)
        #pragma unroll
        for (int k = 0; k < 16; ++k) {
            const int row = 16 * w + k;
            const float4 wa = *(const float4*)&Wc[row * 20 + 0];
            const float4 wb = *(const float4*)&Wc[row * 20 + 4];
            const float4 wv = *(const float4*)&Wc[row * 20 + 8];
            const float4 wd = *(const float4*)&Wc[row * 20 + 12];
            float t0 = fmaf(wa.x, r0[0],  fmaf(wa.y, r0[1],  fmaf(wa.z, r0[2],  wa.w * r0[3])));
            float t1 = fmaf(wb.x, r0[4],  fmaf(wb.y, r0[5],  fmaf(wb.z, r0[6],  wb.w * r0[7])));
            float t2 = fmaf(wv.x, r0[8],  fmaf(wv.y, r0[9],  fmaf(wv.z, r0[10], wv.w * r0[11])));
            float t3 = fmaf(wd.x, r0[12], fmaf(wd.y, r0[13], fmaf(wd.z, r0[14], wd.w * r0[15])));
            acc[k] += (t0 + t1) + (t2 + t3);
        }
    }

    // coalesced stores: for fixed k, lanes l=0..63 write 256B contiguous
    float* __restrict__ outb = out + (size_t)b * 4096;
    #pragma unroll
    for (int k = 0; k < 16; ++k)
        outb[(size_t)(16 * w + k) * 64 + l] = acc[k];
}

extern "C" void kernel_launch(void* const* d_in, const int* in_sizes, int n_in,
                              void* d_out, int out_size, void* d_ws, size_t ws_size,
                              hipStream_t stream)
{
    const float* X = (const float*)d_in[0];
    float* out = (float*)d_out;
    const int B = in_sizes[0] / 4096;   // 8192 matrices of 64x64 fp32
    logeig_kernel<<<dim3(B), dim3(256), 0, stream>>>(X, out);
}

// Round 7
// 5117.285 us; speedup vs baseline: 1.2302x; 1.2302x over previous
//
#include <hip/hip_runtime.h>
#include <math.h>

#define NSW 12  // convergence-verified budget (R2/R5/R6: absmax at bf16 floor)

__device__ __forceinline__ float bperm_f(int addr4, float v) {
    return __int_as_float(__builtin_amdgcn_ds_bpermute(addr4, __float_as_int(v)));
}

// One-sided (Hestenes) Jacobi, circle-method tournament (R2/R5/R6-verified).
// Half-column layout (R5): 2 waves per matrix, wave w owns rows [32w,32w+32),
// lane l holds 32 floats of column l. Main loop is BIT-IDENTICAL to R5's
// (proven: absmax at bf16 floor, no remat — conflict/bperm ratio 1.428).
// R7 change: spill-free epilogue. R5 spilled ~11.5KB/block (acc[32]+r0[16]+
// x[32] ~ 85 live > 64) -> 94MB scratch write-through + occupancy capped at
// 44% -> DS pipe only ~43% busy. New epilogue: two 16-row passes per wave
// (acc[16]) with 8-wide r0 slices; worst-case live ~60 regs.
__global__ __launch_bounds__(128, 4) void logeig_kernel(
    const float* __restrict__ Xg, float* __restrict__ out)
{
    __shared__ __align__(16) float Wc[64 * 20];  // epilogue chunk (16 cols, pad 20)
    __shared__ float gbuf[2][2][64];             // [parity][wave][column] partials
    __shared__ float nbuf[2][64];                // [wave][column] norm resync
    __shared__ float hlds[64];

    const int tid = threadIdx.x;
    const int w   = tid >> 6;     // 0: rows 0-31, 1: rows 32-63
    const int l   = tid & 63;     // owned column
    const int b   = blockIdx.x;

    // ---- load rows [32w,32w+32) of column l (X symmetric -> row l span) ----
    float x[32];
    {
        const float4* __restrict__ Xb4 =
            (const float4*)(Xg + (size_t)b * 4096 + (size_t)l * 64 + 32 * w);
        #pragma unroll
        for (int q = 0; q < 8; ++q) {
            float4 v = Xb4[q];
            x[4 * q + 0] = v.x; x[4 * q + 1] = v.y;
            x[4 * q + 2] = v.z; x[4 * q + 3] = v.w;
        }
    }

    // ---- initial squared norm: half-norms combined across waves ----
    float d;
    {
        float a0 = 0.f, a1 = 0.f, a2 = 0.f, a3 = 0.f;
        #pragma unroll
        for (int k = 0; k < 32; k += 4) {
            a0 = fmaf(x[k + 0], x[k + 0], a0);
            a1 = fmaf(x[k + 1], x[k + 1], a1);
            a2 = fmaf(x[k + 2], x[k + 2], a2);
            a3 = fmaf(x[k + 3], x[k + 3], a3);
        }
        nbuf[w][l] = (a0 + a1) + (a2 + a3);
        __syncthreads();
        d = nbuf[0][l] + nbuf[1][l];   // canonical top+bot, identical on both waves
    }

    // ---- tournament state (identical formulas to R2/R5) ----
    const int m  = l - 1;                       // label; -1 for fixed player col 0
    int pm = (l == 0) ? 0 : ((63 - m) % 63);    // (r - m) mod 63 at r=0
    int p0 = 0;                                 // 32*r mod 63

    for (int sweep = 0; sweep < NSW; ++sweep) {
        for (int r = 0; r < 63; ++r) {
            const int prt  = (l == 0) ? (p0 + 1)
                                      : ((pm == m) ? 0 : (pm + 1));
            const int prt4 = prt << 2;

            // fetch partner half-column + Gram partial (this wave's 32 rows)
            float xp[32];
            float a0 = 0.f, a1 = 0.f, a2 = 0.f, a3 = 0.f;
            #pragma unroll
            for (int k = 0; k < 32; k += 4) {
                xp[k + 0] = bperm_f(prt4, x[k + 0]);
                xp[k + 1] = bperm_f(prt4, x[k + 1]);
                xp[k + 2] = bperm_f(prt4, x[k + 2]);
                xp[k + 3] = bperm_f(prt4, x[k + 3]);
                a0 = fmaf(x[k + 0], xp[k + 0], a0);
                a1 = fmaf(x[k + 1], xp[k + 1], a1);
                a2 = fmaf(x[k + 2], xp[k + 2], a2);
                a3 = fmaf(x[k + 3], xp[k + 3], a3);
            }
            const float gp = (a0 + a1) + (a2 + a3);  // this wave's half of gamma
            const float dq = bperm_f(prt4, d);       // partner's full norm (replicated)

            gbuf[r & 1][w][l] = gp;
            __syncthreads();
            const float go = gbuf[r & 1][1 - w][l];
            const float g  = gp + go;                // commutative -> bit-identical

            const bool lo = l < prt;
            const bool ok = fabsf(g) > 1e-30f;

            // angle from the LO column's perspective (identical on all copies)
            const float num  = lo ? (dq - d) : (d - dq);
            const float zeta = num / (2.f * g);
            const float az   = fabsf(zeta);
            float tl = 1.f / (az + sqrtf(fmaf(az, az, 1.f)));
            tl = (zeta >= 0.f) ? tl : -tl;           // lo-side t
            float tn = lo ? tl : -tl;                // own signed t (hi negates)
            tn = ok ? tn : 0.f;
            const float c = rsqrtf(fmaf(tn, tn, 1.f));
            const float s = c * tn;

            // Rutishauser norm update (identical on both waves)
            d = fmaf(-tn, g, d);

            // half-column update
            #pragma unroll
            for (int k = 0; k < 32; ++k)
                x[k] = fmaf(-s, xp[k], c * x[k]);

            // advance tournament state
            pm = (pm + 1 == 63) ? 0 : (pm + 1);
            p0 += 32; if (p0 >= 63) p0 -= 63;
        }

        // sweep boundary: resync squared norm from actual half-norms
        float a0 = 0.f, a1 = 0.f, a2 = 0.f, a3 = 0.f;
        #pragma unroll
        for (int k = 0; k < 32; k += 4) {
            a0 = fmaf(x[k + 0], x[k + 0], a0);
            a1 = fmaf(x[k + 1], x[k + 1], a1);
            a2 = fmaf(x[k + 2], x[k + 2], a2);
            a3 = fmaf(x[k + 3], x[k + 3], a3);
        }
        __syncthreads();                        // rotations' gbuf reads done
        nbuf[w][l] = (a0 + a1) + (a2 + a3);
        __syncthreads();
        d = nbuf[0][l] + nbuf[1][l];
    }

    // ---- epilogue: out = sum_c h_c w_c w_c^T (spill-free, two 16-row passes) ----
    const float alpha = fmaxf(d, 1e-12f);
    const float h = 0.5f * logf(alpha) / alpha;
    if (w == 0) hlds[l] = h;   // identical value on both waves

    const int cg = l >> 4;     // chunk containing this lane's column
    const int cc = l & 15;     // column index within chunk
    float* __restrict__ outb = out + (size_t)b * 4096;

    for (int rh = 0; rh < 2; ++rh) {
        float acc[16];
        #pragma unroll
        for (int k = 0; k < 16; ++k) acc[k] = 0.f;
        const int rbase = 32 * w + 16 * rh;   // output rows this pass

        for (int gi = 0; gi < 4; ++gi) {
            __syncthreads();   // WAR on Wc (and orders hlds on the first pass)
            if (cg == gi) {
                #pragma unroll
                for (int j = 0; j < 32; ++j) Wc[(32 * w + j) * 20 + cc] = x[j];
            }
            __syncthreads();

            // 8-wide r0 slices keep the live set small
            #pragma unroll
            for (int hh = 0; hh < 2; ++hh) {
                float r0[8];
                #pragma unroll
                for (int j = 0; j < 8; ++j)
                    r0[j] = Wc[l * 20 + 8 * hh + j] * hlds[gi * 16 + 8 * hh + j];
                #pragma unroll
                for (int k = 0; k < 16; ++k) {
                    const int row = rbase + k;
                    const float4 wa = *(const float4*)&Wc[row * 20 + 8 * hh + 0];
                    const float4 wb = *(const float4*)&Wc[row * 20 + 8 * hh + 4];
                    acc[k] += fmaf(wa.x, r0[0], fmaf(wa.y, r0[1],
                                   fmaf(wa.z, r0[2], wa.w * r0[3])))
                            + fmaf(wb.x, r0[4], fmaf(wb.y, r0[5],
                                   fmaf(wb.z, r0[6], wb.w * r0[7])));
                }
            }
        }

        // coalesced stores: for fixed row, lanes l=0..63 write 256B contiguous
        #pragma unroll
        for (int k = 0; k < 16; ++k)
            outb[(size_t)(rbase + k) * 64 + l] = acc[k];
    }
}

extern "C" void kernel_launch(void* const* d_in, const int* in_sizes, int n_in,
                              void* d_out, int out_size, void* d_ws, size_t ws_size,
                              hipStream_t stream)
{
    const float* X = (const float*)d_in[0];
    float* out = (float*)d_out;
    const int B = in_sizes[0] / 4096;   // 8192 matrices of 64x64 fp32
    logeig_kernel<<<dim3(B), dim3(128), 0, stream>>>(X, out);
}